// Round 11
// baseline (439.265 us; speedup 1.0000x reference)
//
#include <hip/hip_runtime.h>

// PSP: syn_t = 0.5*(syn_{t-1} + x_t), tau=2. Shapes (T=64, N=512, C=2048) f32.
//
// R8 post-mortem: dropping the cross-chunk carry was WRONG (first element of
// a chunk attenuates carry by only 0.5; absmax 1.48 matched 0.5*max|carry|).
// Fix: block owns ALL 64 timesteps of a 256-f4-column window, processed as
// 4 sequential LDS-staged chunks; the accumulator carries across chunks in
// registers. Exact recurrence (same as R1, absmax 0.0).
//
// Contiguity theory (R1-R6: all register schedules stuck at ~3 TB/s vs 6.4
// for contiguous fills): load/store phases move 4KB contiguous runs per slab
// for better DRAM page locality. LDS 64KB -> 2 blocks/CU phase overlap.

typedef float f4 __attribute__((ext_vector_type(4)));

#define NC4 (512 * 2048 / 4)   // 262144 f4 columns per timestep
#define CHUNK 16               // timesteps staged per tile
#define NCHUNK 4               // T / CHUNK
#define W 256                  // f4 columns per block (4KB per slab run)
#define NWIN (NC4 / W)         // 1024 blocks

__global__ __launch_bounds__(256) void psp_scan_kernel(
    const f4* __restrict__ in, f4* __restrict__ out) {
    // Bijective XCD swizzle (1024 % 8 == 0): each XCD gets 128 adjacent
    // column windows -> contiguous per-XCD address range.
    const int bid = blockIdx.x;
    const int win = (bid & 7) * (NWIN / 8) + (bid >> 3);

    __shared__ f4 tile[CHUNK][W];          // 64 KB

    const int tid  = threadIdx.x;          // 0..255 == column owner id
    const int wave = tid >> 6;             // 0..3
    const int lane = tid & 63;
    const size_t colBase = (size_t)win * W;

    f4 acc = {0.f, 0.f, 0.f, 0.f};         // carries across chunks — exact

    for (int c = 0; c < NCHUNK; ++c) {
        const size_t base = (size_t)(c * CHUNK) * NC4 + colBase;

        // Load phase: wave w stages slabs 4w..4w+3; each slab is a 4KB
        // contiguous run (4 back-to-back 1KB wave-instructions).
#pragma unroll
        for (int k = 0; k < 4; ++k) {
            const int s = wave * 4 + k;
            const f4* src = in + base + (size_t)s * NC4;
#pragma unroll
            for (int i = 0; i < W / 64; ++i)
                tile[s][i * 64 + lane] = src[i * 64 + lane];
        }
        __syncthreads();

        // Scan phase: thread owns column tid, in place. acc persists.
#pragma unroll
        for (int t = 0; t < CHUNK; ++t) {
            acc = 0.5f * (acc + tile[t][tid]);
            tile[t][tid] = acc;
        }
        __syncthreads();

        // Store phase: same 4KB contiguous runs outbound. No barrier needed
        // before next load: store reads and next-load writes of LDS rows
        // 4w..4w+3 belong to the SAME wave (program-ordered via lgkmcnt).
#pragma unroll
        for (int k = 0; k < 4; ++k) {
            const int s = wave * 4 + k;
            f4* dst = out + base + (size_t)s * NC4;
#pragma unroll
            for (int i = 0; i < W / 64; ++i)
                dst[i * 64 + lane] = tile[s][i * 64 + lane];
        }
    }
}

extern "C" void kernel_launch(void* const* d_in, const int* in_sizes, int n_in,
                              void* d_out, int out_size, void* d_ws, size_t ws_size,
                              hipStream_t stream) {
    const f4* in = (const f4*)d_in[0];
    f4* out = (f4*)d_out;
    psp_scan_kernel<<<NWIN, 256, 0, stream>>>(in, out);
}